// Round 7
// baseline (155.875 us; speedup 1.0000x reference)
//
#include <hip/hip_runtime.h>
#include <math.h>

#define EPSF     1e-12f
#define INV_4PI  0.07957747154594767f
#define LOG2E    1.4426950408889634f

// Z = z_approxbis(f), f already clipped to [0, 0.999999]
__device__ __forceinline__ float zapprox(float f) {
    float f2 = f * f;
    float f4 = f2 * f2;
    float f6 = f4 * f2;
    float f8 = f4 * f4;
    float denom = 3.0f - 1.00651f * f2 - 0.962251f * f4 + 1.47353f * f6 - 0.48953f * f8;
    denom = fmaxf(denom, EPSF);
    float p = 1.0f - 2.0f * (1.0f - f) * (1.0f + 1.01524f * f) / denom;
    return 2.0f * f / fmaxf(1.0f - p, 1e-6f);
}

// z / sinh(z), z >= 0
__device__ __forceinline__ float z_over_sinh(float z) {
    float zz = z * z;
    float series = 1.0f - zz / 6.0f + zz * zz / 120.0f;
    float E = __expf(z);
    float s = 0.5f * (E - 1.0f / E);
    float r = z / s;           // NaN at z==0, discarded by select
    return (z < 1e-4f) ? series : r;
}

// per-species setup: g(dir) = 2^(zx*dx + zy*dy + zz*dz + la)
struct Spec { float zx, zy, zz, la; };

__device__ __forceinline__ Spec setup_spec(float N, float Fx, float Fy, float Fz) {
    N = fmaxf(N, EPSF);
    float nf = sqrtf(Fx * Fx + Fy * Fy + Fz * Fz);
    float f  = fminf(fmaxf(nf / N, 0.0f), 0.999999f);
    float Z  = zapprox(f);
    float A  = N * INV_4PI * z_over_sinh(Z);
    float sc = Z * LOG2E / fmaxf(nf, EPSF);
    Spec s;
    s.zx = Fx * sc; s.zy = Fy * sc; s.zz = Fz * sc;
    s.la = log2f(A);   // A > 0 always; v_log_f32
    return s;
}

// wave-uniform value -> SGPR (readfirstlane); frees a VGPR for loop constants
__device__ __forceinline__ float rfl(float x) {
    return __int_as_float(__builtin_amdgcn_readfirstlane(__float_as_int(x)));
}

__global__ __launch_bounds__(256) void box3d_kernel(
    const float* __restrict__ F4,
    const float* __restrict__ dxp, const float* __restrict__ dyp,
    const float* __restrict__ dzp, const float* __restrict__ qwp,
    float* __restrict__ out, int B, int ndir)
{
    __shared__ float4 sdir[800];   // (dx, dy, dz, w) per direction
    for (int d = threadIdx.x; d < ndir; d += blockDim.x)
        sdir[d] = make_float4(dxp[d], dyp[d], dzp[d], qwp[d]);
    __syncthreads();

    // one batch per WAVE: constants become wave-uniform -> SGPRs
    const int lane = threadIdx.x & 63;
    const int wv   = threadIdx.x >> 6;       // wave index in block (0..3)
    const int b = blockIdx.x * 4 + wv;
    if (b >= B) return;

    // ---- per-batch setup (redundant across the 64 lanes of the wave) ----
    const float4* row = (const float4*)(F4 + (size_t)b * 24);
    float4 r0 = row[0], r1 = row[1], r2 = row[2];   // nu: flavors 0,1,2
    float4 r3 = row[3], r4 = row[4], r5 = row[5];   // nubar: flavors 0,1,2

    Spec s0 = setup_spec(r0.w, r0.x, r0.y, r0.z);                                  // e
    Spec s1 = setup_spec(r3.w, r3.x, r3.y, r3.z);                                  // ebar
    Spec s2 = setup_spec(0.5f * (r1.w + r2.w), 0.5f * (r1.x + r2.x),
                         0.5f * (r1.y + r2.y), 0.5f * (r1.z + r2.z));              // x
    Spec s3 = setup_spec(0.5f * (r4.w + r5.w), 0.5f * (r4.x + r5.x),
                         0.5f * (r4.y + r5.y), 0.5f * (r4.z + r5.z));              // xbar

    // force into SGPRs (wave-uniform by construction)
    float zx0 = rfl(s0.zx), zy0 = rfl(s0.zy), zz0 = rfl(s0.zz), la0 = rfl(s0.la);
    float zx1 = rfl(s1.zx), zy1 = rfl(s1.zy), zz1 = rfl(s1.zz), la1 = rfl(s1.la);
    float zx2 = rfl(s2.zx), zy2 = rfl(s2.zy), zz2 = rfl(s2.zz), la2 = rfl(s2.la);
    float zx3 = rfl(s3.zx), zy3 = rfl(s3.zy), zz3 = rfl(s3.zz), la3 = rfl(s3.la);

    // ---- single pass over directions (64-lane split), masked moment sums ----
    float ip = 0, im = 0;                       // Iplus / Iminus
    float ut0 = 0, ut1 = 0, ut2 = 0, ut3 = 0;   // sum w*m*u        (u = g_e - g_x)
    float up0 = 0, up1 = 0, up2 = 0, up3 = 0;   // sum_{delta>=0} w*m*u
    float vt0 = 0, vt1 = 0, vt2 = 0, vt3 = 0;   // sum w*m*v        (v = g_ebar - g_xbar)
    float vp0 = 0, vp1 = 0, vp2 = 0, vp3 = 0;   // sum_{delta>=0} w*m*v
    float gx0 = 0, gx1 = 0, gx2 = 0, gx3 = 0;   // sum w*m*g_x
    float gy0 = 0, gy1 = 0, gy2 = 0, gy3 = 0;   // sum w*m*g_xbar

    #pragma unroll 2
    for (int d = lane; d < ndir; d += 64) {
        float4 q = sdir[d];
        float g0 = exp2f(fmaf(zx0, q.x, fmaf(zy0, q.y, fmaf(zz0, q.z, la0))));
        float g1 = exp2f(fmaf(zx1, q.x, fmaf(zy1, q.y, fmaf(zz1, q.z, la1))));
        float g2 = exp2f(fmaf(zx2, q.x, fmaf(zy2, q.y, fmaf(zz2, q.z, la2))));
        float g3 = exp2f(fmaf(zx3, q.x, fmaf(zy3, q.y, fmaf(zz3, q.z, la3))));

        float u = g0 - g2, v = g1 - g3;
        float wu = q.w * u,  wv = q.w * v;
        float wd = wu - wv;                      // w * delta; w > 0
        ip += fmaxf(wd, 0.0f);
        im += fmaxf(-wd, 0.0f);
        bool pos = (wd >= 0.0f);
        float wup = pos ? wu : 0.0f;
        float wvp = pos ? wv : 0.0f;
        float w2 = q.w * g2, w3 = q.w * g3;

        ut0 += wu;  up0 += wup;  vt0 += wv;  vp0 += wvp;  gx0 += w2;  gy0 += w3;
        ut1 = fmaf(wu, q.x, ut1);  up1 = fmaf(wup, q.x, up1);
        vt1 = fmaf(wv, q.x, vt1);  vp1 = fmaf(wvp, q.x, vp1);
        gx1 = fmaf(w2, q.x, gx1);  gy1 = fmaf(w3, q.x, gy1);
        ut2 = fmaf(wu, q.y, ut2);  up2 = fmaf(wup, q.y, up2);
        vt2 = fmaf(wv, q.y, vt2);  vp2 = fmaf(wvp, q.y, vp2);
        gx2 = fmaf(w2, q.y, gx2);  gy2 = fmaf(w3, q.y, gy2);
        ut3 = fmaf(wu, q.z, ut3);  up3 = fmaf(wup, q.z, up3);
        vt3 = fmaf(wv, q.z, vt3);  vp3 = fmaf(wvp, q.z, vp3);
        gx3 = fmaf(w2, q.z, gx3);  gy3 = fmaf(w3, q.z, gy3);
    }

    // ---- butterfly reduction across the full 64-lane wave (6 stages) ----
    #pragma unroll
    for (int msk = 1; msk <= 32; msk <<= 1) {
        ip  += __shfl_xor(ip,  msk);  im  += __shfl_xor(im,  msk);
        ut0 += __shfl_xor(ut0, msk);  ut1 += __shfl_xor(ut1, msk);
        ut2 += __shfl_xor(ut2, msk);  ut3 += __shfl_xor(ut3, msk);
        up0 += __shfl_xor(up0, msk);  up1 += __shfl_xor(up1, msk);
        up2 += __shfl_xor(up2, msk);  up3 += __shfl_xor(up3, msk);
        vt0 += __shfl_xor(vt0, msk);  vt1 += __shfl_xor(vt1, msk);
        vt2 += __shfl_xor(vt2, msk);  vt3 += __shfl_xor(vt3, msk);
        vp0 += __shfl_xor(vp0, msk);  vp1 += __shfl_xor(vp1, msk);
        vp2 += __shfl_xor(vp2, msk);  vp3 += __shfl_xor(vp3, msk);
        gx0 += __shfl_xor(gx0, msk);  gx1 += __shfl_xor(gx1, msk);
        gx2 += __shfl_xor(gx2, msk);  gx3 += __shfl_xor(gx3, msk);
        gy0 += __shfl_xor(gy0, msk);  gy1 += __shfl_xor(gy1, msk);
        gy2 += __shfl_xor(gy2, msk);  gy3 += __shfl_xor(gy3, msk);
    }

    // ---- survival coefficients ----
    float Ips = fmaxf(ip, EPSF), Ims = fmaxf(im, EPSF);
    const float third = 1.0f / 3.0f;
    float cp, cn;
    if (ip < im) {
        cp = third;
        cn = fminf(fmaxf(1.0f - (2.0f / 3.0f) * (Ips / Ims), 0.0f), 1.0f);
    } else {
        cp = fminf(fmaxf(1.0f - (2.0f / 3.0f) * (Ims / Ips), 0.0f), 1.0f);
        cn = third;
    }

    // ---- final moments: P = cp*up + cn*(ut-up); out per reference layout ----
    float P0 = cp * up0 + cn * (ut0 - up0), Q0 = cp * vp0 + cn * (vt0 - vp0);
    float P1 = cp * up1 + cn * (ut1 - up1), Q1 = cp * vp1 + cn * (vt1 - vp1);
    float P2 = cp * up2 + cn * (ut2 - up2), Q2 = cp * vp2 + cn * (vt2 - vp2);
    float P3 = cp * up3 + cn * (ut3 - up3), Q3 = cp * vp3 + cn * (vt3 - vp3);

    // memory layout per batch (6 float4): [e, x, x, ebar, xbar, xbar], each (Fx,Fy,Fz,N)
    float4* o4 = (float4*)out + (size_t)b * 6;
    if (lane == 0) {
        o4[0] = make_float4(gx1 + P1, gx2 + P2, gx3 + P3, gx0 + P0);                       // e
    } else if (lane == 1) {
        o4[1] = make_float4(gx1 + 0.5f * (ut1 - P1), gx2 + 0.5f * (ut2 - P2),
                            gx3 + 0.5f * (ut3 - P3), gx0 + 0.5f * (ut0 - P0));             // x
    } else if (lane == 2) {
        o4[2] = make_float4(gx1 + 0.5f * (ut1 - P1), gx2 + 0.5f * (ut2 - P2),
                            gx3 + 0.5f * (ut3 - P3), gx0 + 0.5f * (ut0 - P0));             // x
    } else if (lane == 3) {
        o4[3] = make_float4(gy1 + Q1, gy2 + Q2, gy3 + Q3, gy0 + Q0);                       // ebar
    } else if (lane == 4) {
        o4[4] = make_float4(gy1 + 0.5f * (vt1 - Q1), gy2 + 0.5f * (vt2 - Q2),
                            gy3 + 0.5f * (vt3 - Q3), gy0 + 0.5f * (vt0 - Q0));             // xbar
    } else if (lane == 5) {
        o4[5] = make_float4(gy1 + 0.5f * (vt1 - Q1), gy2 + 0.5f * (vt2 - Q2),
                            gy3 + 0.5f * (vt3 - Q3), gy0 + 0.5f * (vt0 - Q0));             // xbar
    } else if (lane == 6) {
        out[(size_t)B * 24 + b] = sqrtf(fmaxf(ip * im, 0.0f));                             // growth
    }
}

extern "C" void kernel_launch(void* const* d_in, const int* in_sizes, int n_in,
                              void* d_out, int out_size, void* d_ws, size_t ws_size,
                              hipStream_t stream) {
    const float* F4 = (const float*)d_in[0];
    const float* dx = (const float*)d_in[1];
    const float* dy = (const float*)d_in[2];
    const float* dz = (const float*)d_in[3];
    const float* qw = (const float*)d_in[4];
    float* out = (float*)d_out;

    int B = in_sizes[0] / 24;     // (B, 2, 3, 4)
    int ndir = in_sizes[1];       // 800
    int blocks = (B + 3) / 4;     // 1 batch per wave, 4 waves per 256-thread block
    box3d_kernel<<<blocks, 256, 0, stream>>>(F4, dx, dy, dz, qw, out, B, ndir);
}

// Round 8
// 105.218 us; speedup vs baseline: 1.4814x; 1.4814x over previous
//
#include <hip/hip_runtime.h>
#include <math.h>

#define EPSF     1e-12f
#define INV_4PI  0.07957747154594767f
#define LOG2E    1.4426950408889634f

typedef float v2f __attribute__((ext_vector_type(2)));

#if __has_builtin(__builtin_elementwise_fma)
#define FMA2(a, b, c) __builtin_elementwise_fma((a), (b), (c))
#else
#define FMA2(a, b, c) ((a) * (b) + (c))
#endif
#if __has_builtin(__builtin_elementwise_max)
#define MAX2(a, b) __builtin_elementwise_max((a), (b))
#else
static __device__ __forceinline__ v2f MAX2(v2f a, v2f b) {
    v2f r; r.x = fmaxf(a.x, b.x); r.y = fmaxf(a.y, b.y); return r;
}
#endif

// raw hardware exp2: single v_exp_f32. Safe here: |arg| < ~50, no subnormal
// range, so the OCML libcall's fixup path (what plain exp2f links to) is
// pure overhead (~6 inst per call, 8 calls/iter).
#define EXP2(x) __builtin_amdgcn_exp2f(x)

// Z = z_approxbis(f), f already clipped to [0, 0.999999]
__device__ __forceinline__ float zapprox(float f) {
    float f2 = f * f;
    float f4 = f2 * f2;
    float f6 = f4 * f2;
    float f8 = f4 * f4;
    float denom = 3.0f - 1.00651f * f2 - 0.962251f * f4 + 1.47353f * f6 - 0.48953f * f8;
    denom = fmaxf(denom, EPSF);
    float p = 1.0f - 2.0f * (1.0f - f) * (1.0f + 1.01524f * f) / denom;
    return 2.0f * f / fmaxf(1.0f - p, 1e-6f);
}

// z / sinh(z), z >= 0
__device__ __forceinline__ float z_over_sinh(float z) {
    float zz = z * z;
    float series = 1.0f - zz / 6.0f + zz * zz / 120.0f;
    float E = __expf(z);
    float s = 0.5f * (E - 1.0f / E);
    float r = z / s;           // NaN at z==0, discarded by select
    return (z < 1e-4f) ? series : r;
}

// per-species setup: g(dir) = 2^(zx*dx + zy*dy + zz*dz + la)
struct Spec { float zx, zy, zz, la; };

__device__ __forceinline__ Spec setup_spec(float N, float Fx, float Fy, float Fz) {
    N = fmaxf(N, EPSF);
    float nf = sqrtf(Fx * Fx + Fy * Fy + Fz * Fz);
    float f  = fminf(fmaxf(nf / N, 0.0f), 0.999999f);
    float Z  = zapprox(f);
    float A  = N * INV_4PI * z_over_sinh(Z);
    float sc = Z * LOG2E / fmaxf(nf, EPSF);
    Spec s;
    s.zx = Fx * sc; s.zy = Fy * sc; s.zz = Fz * sc;
    s.la = log2f(A);   // A > 0 always; v_log_f32
    return s;
}

__device__ __forceinline__ v2f bcast(float x) { v2f r; r.x = x; r.y = x; return r; }

// 2nd arg = min waves per EU = 2 -> VGPR budget up to 256/wave. Without this
// the allocator targets 8 waves/EU (64 VGPRs), parks the 26 accumulators in
// AGPRs, and wraps every update in v_accvgpr_read/write (~3x dynamic VALU —
// the measured bloat in R5/R6/R7).
__global__ __launch_bounds__(256, 2) void box3d_kernel(
    const float* __restrict__ F4,
    const float* __restrict__ dxp, const float* __restrict__ dyp,
    const float* __restrict__ dzp, const float* __restrict__ qwp,
    float* __restrict__ out, int B, int ndir)
{
    // SoA LDS: float2 loads per pair of directions; 16-lane stride-2 access
    // is only 2-way bank aliasing (free on CDNA4).
    __shared__ float sqx[800], sqy[800], sqz[800], sqw[800];
    for (int d = threadIdx.x; d < ndir; d += blockDim.x) {
        sqx[d] = dxp[d]; sqy[d] = dyp[d]; sqz[d] = dzp[d]; sqw[d] = qwp[d];
    }
    __syncthreads();

    const int sub = threadIdx.x & 15;        // lane within 16-group
    const int grp = threadIdx.x >> 4;        // 16 groups per 256-thread block
    const int b = blockIdx.x * 16 + grp;
    if (b >= B) return;

    // ---- per-batch setup (redundant across the 16 lanes of a group) ----
    const float4* row = (const float4*)(F4 + (size_t)b * 24);
    float4 r0 = row[0], r1 = row[1], r2 = row[2];   // nu: flavors 0,1,2
    float4 r3 = row[3], r4 = row[4], r5 = row[5];   // nubar: flavors 0,1,2

    Spec s0 = setup_spec(r0.w, r0.x, r0.y, r0.z);                                  // e
    Spec s1 = setup_spec(r3.w, r3.x, r3.y, r3.z);                                  // ebar
    Spec s2 = setup_spec(0.5f * (r1.w + r2.w), 0.5f * (r1.x + r2.x),
                         0.5f * (r1.y + r2.y), 0.5f * (r1.z + r2.z));              // x
    Spec s3 = setup_spec(0.5f * (r4.w + r5.w), 0.5f * (r4.x + r5.x),
                         0.5f * (r4.y + r5.y), 0.5f * (r4.z + r5.z));              // xbar

    v2f zx0 = bcast(s0.zx), zy0 = bcast(s0.zy), zz0 = bcast(s0.zz), la0 = bcast(s0.la);
    v2f zx1 = bcast(s1.zx), zy1 = bcast(s1.zy), zz1 = bcast(s1.zz), la1 = bcast(s1.la);
    v2f zx2 = bcast(s2.zx), zy2 = bcast(s2.zy), zz2 = bcast(s2.zz), la2 = bcast(s2.la);
    v2f zx3 = bcast(s3.zx), zy3 = bcast(s3.zy), zz3 = bcast(s3.zz), la3 = bcast(s3.la);

    // ---- single pass, 2 directions/iter (packed fp32): masked moment sums ----
    const v2f zero = bcast(0.0f);
    v2f aip = zero, aim = zero;
    v2f aut0 = zero, aut1 = zero, aut2 = zero, aut3 = zero;
    v2f aup0 = zero, aup1 = zero, aup2 = zero, aup3 = zero;
    v2f avt0 = zero, avt1 = zero, avt2 = zero, avt3 = zero;
    v2f avp0 = zero, avp1 = zero, avp2 = zero, avp3 = zero;
    v2f agx0 = zero, agx1 = zero, agx2 = zero, agx3 = zero;
    v2f agy0 = zero, agy1 = zero, agy2 = zero, agy3 = zero;

    const int npair = ndir >> 1;             // ndir = 800 (even)
    for (int p = sub; p < npair; p += 16) {
        int d0 = p * 2;
        v2f qx = *(const v2f*)&sqx[d0];
        v2f qy = *(const v2f*)&sqy[d0];
        v2f qz = *(const v2f*)&sqz[d0];
        v2f qw = *(const v2f*)&sqw[d0];

        v2f t0 = FMA2(zx0, qx, FMA2(zy0, qy, FMA2(zz0, qz, la0)));
        v2f t1 = FMA2(zx1, qx, FMA2(zy1, qy, FMA2(zz1, qz, la1)));
        v2f t2 = FMA2(zx2, qx, FMA2(zy2, qy, FMA2(zz2, qz, la2)));
        v2f t3 = FMA2(zx3, qx, FMA2(zy3, qy, FMA2(zz3, qz, la3)));
        v2f g0, g1, g2, g3;
        g0.x = EXP2(t0.x); g0.y = EXP2(t0.y);
        g1.x = EXP2(t1.x); g1.y = EXP2(t1.y);
        g2.x = EXP2(t2.x); g2.y = EXP2(t2.y);
        g3.x = EXP2(t3.x); g3.y = EXP2(t3.y);

        v2f u = g0 - g2, v = g1 - g3;
        v2f wu = qw * u, wv = qw * v;
        v2f wd = wu - wv;                    // w * delta; w > 0 so sign(wd)=sign(delta)
        aip += MAX2(wd, zero);
        aim += MAX2(-wd, zero);

        v2f wup, wvp;                        // masked (delta >= 0) terms
        wup.x = (wd.x >= 0.0f) ? wu.x : 0.0f;
        wup.y = (wd.y >= 0.0f) ? wu.y : 0.0f;
        wvp.x = (wd.x >= 0.0f) ? wv.x : 0.0f;
        wvp.y = (wd.y >= 0.0f) ? wv.y : 0.0f;
        v2f w2 = qw * g2, w3 = qw * g3;

        aut0 += wu;  aup0 += wup;  avt0 += wv;  avp0 += wvp;  agx0 += w2;  agy0 += w3;
        aut1 = FMA2(wu, qx, aut1);  aup1 = FMA2(wup, qx, aup1);
        avt1 = FMA2(wv, qx, avt1);  avp1 = FMA2(wvp, qx, avp1);
        agx1 = FMA2(w2, qx, agx1);  agy1 = FMA2(w3, qx, agy1);
        aut2 = FMA2(wu, qy, aut2);  aup2 = FMA2(wup, qy, aup2);
        avt2 = FMA2(wv, qy, avt2);  avp2 = FMA2(wvp, qy, avp2);
        agx2 = FMA2(w2, qy, agx2);  agy2 = FMA2(w3, qy, agy2);
        aut3 = FMA2(wu, qz, aut3);  aup3 = FMA2(wup, qz, aup3);
        avt3 = FMA2(wv, qz, avt3);  avp3 = FMA2(wvp, qz, avp3);
        agx3 = FMA2(w2, qz, agx3);  agy3 = FMA2(w3, qz, agy3);
    }

    // ---- collapse packed pairs, then butterfly over the 16-lane group ----
    float ip  = aip.x + aip.y,   im  = aim.x + aim.y;
    float ut0 = aut0.x + aut0.y, ut1 = aut1.x + aut1.y, ut2 = aut2.x + aut2.y, ut3 = aut3.x + aut3.y;
    float up0 = aup0.x + aup0.y, up1 = aup1.x + aup1.y, up2 = aup2.x + aup2.y, up3 = aup3.x + aup3.y;
    float vt0 = avt0.x + avt0.y, vt1 = avt1.x + avt1.y, vt2 = avt2.x + avt2.y, vt3 = avt3.x + avt3.y;
    float vp0 = avp0.x + avp0.y, vp1 = avp1.x + avp1.y, vp2 = avp2.x + avp2.y, vp3 = avp3.x + avp3.y;
    float gx0 = agx0.x + agx0.y, gx1 = agx1.x + agx1.y, gx2 = agx2.x + agx2.y, gx3 = agx3.x + agx3.y;
    float gy0 = agy0.x + agy0.y, gy1 = agy1.x + agy1.y, gy2 = agy2.x + agy2.y, gy3 = agy3.x + agy3.y;

    #pragma unroll
    for (int msk = 1; msk <= 8; msk <<= 1) {
        ip  += __shfl_xor(ip,  msk);  im  += __shfl_xor(im,  msk);
        ut0 += __shfl_xor(ut0, msk);  ut1 += __shfl_xor(ut1, msk);
        ut2 += __shfl_xor(ut2, msk);  ut3 += __shfl_xor(ut3, msk);
        up0 += __shfl_xor(up0, msk);  up1 += __shfl_xor(up1, msk);
        up2 += __shfl_xor(up2, msk);  up3 += __shfl_xor(up3, msk);
        vt0 += __shfl_xor(vt0, msk);  vt1 += __shfl_xor(vt1, msk);
        vt2 += __shfl_xor(vt2, msk);  vt3 += __shfl_xor(vt3, msk);
        vp0 += __shfl_xor(vp0, msk);  vp1 += __shfl_xor(vp1, msk);
        vp2 += __shfl_xor(vp2, msk);  vp3 += __shfl_xor(vp3, msk);
        gx0 += __shfl_xor(gx0, msk);  gx1 += __shfl_xor(gx1, msk);
        gx2 += __shfl_xor(gx2, msk);  gx3 += __shfl_xor(gx3, msk);
        gy0 += __shfl_xor(gy0, msk);  gy1 += __shfl_xor(gy1, msk);
        gy2 += __shfl_xor(gy2, msk);  gy3 += __shfl_xor(gy3, msk);
    }

    // ---- survival coefficients ----
    float Ips = fmaxf(ip, EPSF), Ims = fmaxf(im, EPSF);
    const float third = 1.0f / 3.0f;
    float cp, cn;
    if (ip < im) {
        cp = third;
        cn = fminf(fmaxf(1.0f - (2.0f / 3.0f) * (Ips / Ims), 0.0f), 1.0f);
    } else {
        cp = fminf(fmaxf(1.0f - (2.0f / 3.0f) * (Ims / Ips), 0.0f), 1.0f);
        cn = third;
    }

    // ---- final moments: P = cp*up + cn*(ut-up); out per reference layout ----
    float P0 = cp * up0 + cn * (ut0 - up0), Q0 = cp * vp0 + cn * (vt0 - vp0);
    float P1 = cp * up1 + cn * (ut1 - up1), Q1 = cp * vp1 + cn * (vt1 - vp1);
    float P2 = cp * up2 + cn * (ut2 - up2), Q2 = cp * vp2 + cn * (vt2 - vp2);
    float P3 = cp * up3 + cn * (ut3 - up3), Q3 = cp * vp3 + cn * (vt3 - vp3);

    // memory layout per batch (6 float4): [e, x, x, ebar, xbar, xbar], each (Fx,Fy,Fz,N)
    float4* o4 = (float4*)out + (size_t)b * 6;
    if (sub == 0) {
        o4[0] = make_float4(gx1 + P1, gx2 + P2, gx3 + P3, gx0 + P0);                       // e
    } else if (sub == 1) {
        o4[1] = make_float4(gx1 + 0.5f * (ut1 - P1), gx2 + 0.5f * (ut2 - P2),
                            gx3 + 0.5f * (ut3 - P3), gx0 + 0.5f * (ut0 - P0));             // x
    } else if (sub == 2) {
        o4[2] = make_float4(gx1 + 0.5f * (ut1 - P1), gx2 + 0.5f * (ut2 - P2),
                            gx3 + 0.5f * (ut3 - P3), gx0 + 0.5f * (ut0 - P0));             // x
    } else if (sub == 3) {
        o4[3] = make_float4(gy1 + Q1, gy2 + Q2, gy3 + Q3, gy0 + Q0);                       // ebar
    } else if (sub == 4) {
        o4[4] = make_float4(gy1 + 0.5f * (vt1 - Q1), gy2 + 0.5f * (vt2 - Q2),
                            gy3 + 0.5f * (vt3 - Q3), gy0 + 0.5f * (vt0 - Q0));             // xbar
    } else if (sub == 5) {
        o4[5] = make_float4(gy1 + 0.5f * (vt1 - Q1), gy2 + 0.5f * (vt2 - Q2),
                            gy3 + 0.5f * (vt3 - Q3), gy0 + 0.5f * (vt0 - Q0));             // xbar
    } else if (sub == 6) {
        out[(size_t)B * 24 + b] = sqrtf(fmaxf(ip * im, 0.0f));                             // growth
    }
}

extern "C" void kernel_launch(void* const* d_in, const int* in_sizes, int n_in,
                              void* d_out, int out_size, void* d_ws, size_t ws_size,
                              hipStream_t stream) {
    const float* F4 = (const float*)d_in[0];
    const float* dx = (const float*)d_in[1];
    const float* dy = (const float*)d_in[2];
    const float* dz = (const float*)d_in[3];
    const float* qw = (const float*)d_in[4];
    float* out = (float*)d_out;

    int B = in_sizes[0] / 24;     // (B, 2, 3, 4)
    int ndir = in_sizes[1];       // 800
    int blocks = (B + 15) / 16;   // 16 batch elements per 256-thread block
    box3d_kernel<<<blocks, 256, 0, stream>>>(F4, dx, dy, dz, qw, out, B, ndir);
}

// Round 9
// 96.373 us; speedup vs baseline: 1.6174x; 1.0918x over previous
//
#include <hip/hip_runtime.h>
#include <math.h>

#define EPSF     1e-12f
#define INV_4PI  0.07957747154594767f
#define LOG2E    1.4426950408889634f

typedef float v2f __attribute__((ext_vector_type(2)));

#if __has_builtin(__builtin_elementwise_fma)
#define FMA2(a, b, c) __builtin_elementwise_fma((a), (b), (c))
#else
#define FMA2(a, b, c) ((a) * (b) + (c))
#endif

// raw hardware exp2: single v_exp_f32 (|arg| < ~50 here, no subnormal fixup needed)
#define EXP2(x) __builtin_amdgcn_exp2f(x)

// Z = z_approxbis(f), f already clipped to [0, 0.999999]
__device__ __forceinline__ float zapprox(float f) {
    float f2 = f * f;
    float f4 = f2 * f2;
    float f6 = f4 * f2;
    float f8 = f4 * f4;
    float denom = 3.0f - 1.00651f * f2 - 0.962251f * f4 + 1.47353f * f6 - 0.48953f * f8;
    denom = fmaxf(denom, EPSF);
    float p = 1.0f - 2.0f * (1.0f - f) * (1.0f + 1.01524f * f) / denom;
    return 2.0f * f / fmaxf(1.0f - p, 1e-6f);
}

// z / sinh(z), z >= 0
__device__ __forceinline__ float z_over_sinh(float z) {
    float zz = z * z;
    float series = 1.0f - zz / 6.0f + zz * zz / 120.0f;
    float E = __expf(z);
    float s = 0.5f * (E - 1.0f / E);
    float r = z / s;           // NaN at z==0, discarded by select
    return (z < 1e-4f) ? series : r;
}

// per-species: g(dir) = 2^(zx*dx + zy*dy + zz*dz + la)
__device__ __forceinline__ float4 setup_spec(float N, float Fx, float Fy, float Fz) {
    N = fmaxf(N, EPSF);
    float nf = sqrtf(Fx * Fx + Fy * Fy + Fz * Fz);
    float f  = fminf(fmaxf(nf / N, 0.0f), 0.999999f);
    float Z  = zapprox(f);
    float A  = N * INV_4PI * z_over_sinh(Z);
    float sc = Z * LOG2E / fmaxf(nf, EPSF);
    return make_float4(Fx * sc, Fy * sc, Fz * sc, log2f(A));
}

// ---- kernel 1: per-(batch,species) Spec precompute -> d_ws --------------
// Pulls the division/transcendental-heavy setup (and its register peak) out
// of the hot kernel; runs once per batch instead of redundantly on 16 lanes.
__global__ __launch_bounds__(256) void spec_kernel(
    const float* __restrict__ F4, float4* __restrict__ ws, int B)
{
    int t = blockIdx.x * blockDim.x + threadIdx.x;
    if (t >= 4 * B) return;
    int b = t >> 2, s = t & 3;
    const float4* row = (const float4*)(F4 + (size_t)b * 24);
    float N, Fx, Fy, Fz;
    if (s == 0) {                       // e
        float4 a = row[0];  N = a.w; Fx = a.x; Fy = a.y; Fz = a.z;
    } else if (s == 1) {                // ebar
        float4 a = row[3];  N = a.w; Fx = a.x; Fy = a.y; Fz = a.z;
    } else if (s == 2) {                // x = mean(flavors 1,2) of nu
        float4 a = row[1], c = row[2];
        N = 0.5f * (a.w + c.w); Fx = 0.5f * (a.x + c.x);
        Fy = 0.5f * (a.y + c.y); Fz = 0.5f * (a.z + c.z);
    } else {                            // xbar
        float4 a = row[4], c = row[5];
        N = 0.5f * (a.w + c.w); Fx = 0.5f * (a.x + c.x);
        Fy = 0.5f * (a.y + c.y); Fz = 0.5f * (a.z + c.z);
    }
    ws[(size_t)b * 4 + s] = setup_spec(N, Fx, Fy, Fz);
}

__device__ __forceinline__ v2f bcast(float x) { v2f r; r.x = x; r.y = x; return r; }

// ---- kernel 2: hot quadrature loop --------------------------------------
// launch_bounds min-waves/EU = 3: VGPR cap ~170 — enough for the ~104-reg
// loop state in true VGPRs (no AGPR parking), while forcing >=3 waves/EU.
__global__ __launch_bounds__(256, 3) void box3d_kernel(
    const float4* __restrict__ ws,
    const float* __restrict__ dxp, const float* __restrict__ dyp,
    const float* __restrict__ dzp, const float* __restrict__ qwp,
    float* __restrict__ out, int B, int ndir)
{
    __shared__ float sqx[800], sqy[800], sqz[800], sqw[800];
    for (int d = threadIdx.x; d < ndir; d += blockDim.x) {
        sqx[d] = dxp[d]; sqy[d] = dyp[d]; sqz[d] = dzp[d]; sqw[d] = qwp[d];
    }
    __syncthreads();

    const int sub = threadIdx.x & 15;        // lane within 16-group
    const int grp = threadIdx.x >> 4;        // 16 groups per 256-thread block
    const int b = blockIdx.x * 16 + grp;
    if (b >= B) return;

    // specs precomputed by spec_kernel (broadcast loads within the group)
    const float4* wsb = ws + (size_t)b * 4;
    float4 f0 = wsb[0], f1 = wsb[1], f2 = wsb[2], f3 = wsb[3];
    v2f zx0 = bcast(f0.x), zy0 = bcast(f0.y), zz0 = bcast(f0.z), la0 = bcast(f0.w);
    v2f zx1 = bcast(f1.x), zy1 = bcast(f1.y), zz1 = bcast(f1.z), la1 = bcast(f1.w);
    v2f zx2 = bcast(f2.x), zy2 = bcast(f2.y), zz2 = bcast(f2.z), la2 = bcast(f2.w);
    v2f zx3 = bcast(f3.x), zy3 = bcast(f3.y), zz3 = bcast(f3.z), la3 = bcast(f3.w);

    // masked moment sums; ip/im derived afterwards from up0/vp0/ut0/vt0
    // (identical masked sums; all magnitudes O(1) so the subtraction is safe)
    const v2f zero = bcast(0.0f);
    v2f aut0 = zero, aut1 = zero, aut2 = zero, aut3 = zero;
    v2f aup0 = zero, aup1 = zero, aup2 = zero, aup3 = zero;
    v2f avt0 = zero, avt1 = zero, avt2 = zero, avt3 = zero;
    v2f avp0 = zero, avp1 = zero, avp2 = zero, avp3 = zero;
    v2f agx0 = zero, agx1 = zero, agx2 = zero, agx3 = zero;
    v2f agy0 = zero, agy1 = zero, agy2 = zero, agy3 = zero;

    const int npair = ndir >> 1;             // 400
    for (int p = sub; p < npair; p += 16) {
        int d0 = p * 2;
        v2f qx = *(const v2f*)&sqx[d0];
        v2f qy = *(const v2f*)&sqy[d0];
        v2f qz = *(const v2f*)&sqz[d0];
        v2f qw = *(const v2f*)&sqw[d0];

        v2f t0 = FMA2(zx0, qx, FMA2(zy0, qy, FMA2(zz0, qz, la0)));
        v2f t1 = FMA2(zx1, qx, FMA2(zy1, qy, FMA2(zz1, qz, la1)));
        v2f t2 = FMA2(zx2, qx, FMA2(zy2, qy, FMA2(zz2, qz, la2)));
        v2f t3 = FMA2(zx3, qx, FMA2(zy3, qy, FMA2(zz3, qz, la3)));
        v2f g0, g1, g2, g3;
        g0.x = EXP2(t0.x); g0.y = EXP2(t0.y);
        g1.x = EXP2(t1.x); g1.y = EXP2(t1.y);
        g2.x = EXP2(t2.x); g2.y = EXP2(t2.y);
        g3.x = EXP2(t3.x); g3.y = EXP2(t3.y);

        v2f u = g0 - g2, v = g1 - g3;        // delta = u - v; w > 0
        v2f wu = qw * u, wv = qw * v;
        v2f wup, wvp;                        // masked (delta >= 0) terms
        wup.x = (u.x >= v.x) ? wu.x : 0.0f;
        wup.y = (u.y >= v.y) ? wu.y : 0.0f;
        wvp.x = (u.x >= v.x) ? wv.x : 0.0f;
        wvp.y = (u.y >= v.y) ? wv.y : 0.0f;
        v2f w2 = qw * g2, w3 = qw * g3;

        aut0 += wu;  aup0 += wup;  avt0 += wv;  avp0 += wvp;  agx0 += w2;  agy0 += w3;
        aut1 = FMA2(wu, qx, aut1);  aup1 = FMA2(wup, qx, aup1);
        avt1 = FMA2(wv, qx, avt1);  avp1 = FMA2(wvp, qx, avp1);
        agx1 = FMA2(w2, qx, agx1);  agy1 = FMA2(w3, qx, agy1);
        aut2 = FMA2(wu, qy, aut2);  aup2 = FMA2(wup, qy, aup2);
        avt2 = FMA2(wv, qy, avt2);  avp2 = FMA2(wvp, qy, avp2);
        agx2 = FMA2(w2, qy, agx2);  agy2 = FMA2(w3, qy, agy2);
        aut3 = FMA2(wu, qz, aut3);  aup3 = FMA2(wup, qz, aup3);
        avt3 = FMA2(wv, qz, avt3);  avp3 = FMA2(wvp, qz, avp3);
        agx3 = FMA2(w2, qz, agx3);  agy3 = FMA2(w3, qz, agy3);
    }

    // ---- collapse packed pairs, then butterfly over the 16-lane group ----
    float ut0 = aut0.x + aut0.y, ut1 = aut1.x + aut1.y, ut2 = aut2.x + aut2.y, ut3 = aut3.x + aut3.y;
    float up0 = aup0.x + aup0.y, up1 = aup1.x + aup1.y, up2 = aup2.x + aup2.y, up3 = aup3.x + aup3.y;
    float vt0 = avt0.x + avt0.y, vt1 = avt1.x + avt1.y, vt2 = avt2.x + avt2.y, vt3 = avt3.x + avt3.y;
    float vp0 = avp0.x + avp0.y, vp1 = avp1.x + avp1.y, vp2 = avp2.x + avp2.y, vp3 = avp3.x + avp3.y;
    float gx0 = agx0.x + agx0.y, gx1 = agx1.x + agx1.y, gx2 = agx2.x + agx2.y, gx3 = agx3.x + agx3.y;
    float gy0 = agy0.x + agy0.y, gy1 = agy1.x + agy1.y, gy2 = agy2.x + agy2.y, gy3 = agy3.x + agy3.y;

    #pragma unroll
    for (int msk = 1; msk <= 8; msk <<= 1) {
        ut0 += __shfl_xor(ut0, msk);  ut1 += __shfl_xor(ut1, msk);
        ut2 += __shfl_xor(ut2, msk);  ut3 += __shfl_xor(ut3, msk);
        up0 += __shfl_xor(up0, msk);  up1 += __shfl_xor(up1, msk);
        up2 += __shfl_xor(up2, msk);  up3 += __shfl_xor(up3, msk);
        vt0 += __shfl_xor(vt0, msk);  vt1 += __shfl_xor(vt1, msk);
        vt2 += __shfl_xor(vt2, msk);  vt3 += __shfl_xor(vt3, msk);
        vp0 += __shfl_xor(vp0, msk);  vp1 += __shfl_xor(vp1, msk);
        vp2 += __shfl_xor(vp2, msk);  vp3 += __shfl_xor(vp3, msk);
        gx0 += __shfl_xor(gx0, msk);  gx1 += __shfl_xor(gx1, msk);
        gx2 += __shfl_xor(gx2, msk);  gx3 += __shfl_xor(gx3, msk);
        gy0 += __shfl_xor(gy0, msk);  gy1 += __shfl_xor(gy1, msk);
        gy2 += __shfl_xor(gy2, msk);  gy3 += __shfl_xor(gy3, msk);
    }

    // Iplus = sum_{delta>=0} w*delta = up0 - vp0 (identical masked sums)
    // Iminus = Iplus - sum w*delta   = ip - (ut0 - vt0)
    float ip = fmaxf(up0 - vp0, 0.0f);
    float im = fmaxf(ip - ut0 + vt0, 0.0f);

    float Ips = fmaxf(ip, EPSF), Ims = fmaxf(im, EPSF);
    const float third = 1.0f / 3.0f;
    float cp, cn;
    if (ip < im) {
        cp = third;
        cn = fminf(fmaxf(1.0f - (2.0f / 3.0f) * (Ips / Ims), 0.0f), 1.0f);
    } else {
        cp = fminf(fmaxf(1.0f - (2.0f / 3.0f) * (Ims / Ips), 0.0f), 1.0f);
        cn = third;
    }

    // ---- final moments: P = cp*up + cn*(ut-up); out per reference layout ----
    float P0 = cp * up0 + cn * (ut0 - up0), Q0 = cp * vp0 + cn * (vt0 - vp0);
    float P1 = cp * up1 + cn * (ut1 - up1), Q1 = cp * vp1 + cn * (vt1 - vp1);
    float P2 = cp * up2 + cn * (ut2 - up2), Q2 = cp * vp2 + cn * (vt2 - vp2);
    float P3 = cp * up3 + cn * (ut3 - up3), Q3 = cp * vp3 + cn * (vt3 - vp3);

    // memory layout per batch (6 float4): [e, x, x, ebar, xbar, xbar], each (Fx,Fy,Fz,N)
    float4* o4 = (float4*)out + (size_t)b * 6;
    if (sub == 0) {
        o4[0] = make_float4(gx1 + P1, gx2 + P2, gx3 + P3, gx0 + P0);                       // e
    } else if (sub == 1) {
        o4[1] = make_float4(gx1 + 0.5f * (ut1 - P1), gx2 + 0.5f * (ut2 - P2),
                            gx3 + 0.5f * (ut3 - P3), gx0 + 0.5f * (ut0 - P0));             // x
    } else if (sub == 2) {
        o4[2] = make_float4(gx1 + 0.5f * (ut1 - P1), gx2 + 0.5f * (ut2 - P2),
                            gx3 + 0.5f * (ut3 - P3), gx0 + 0.5f * (ut0 - P0));             // x
    } else if (sub == 3) {
        o4[3] = make_float4(gy1 + Q1, gy2 + Q2, gy3 + Q3, gy0 + Q0);                       // ebar
    } else if (sub == 4) {
        o4[4] = make_float4(gy1 + 0.5f * (vt1 - Q1), gy2 + 0.5f * (vt2 - Q2),
                            gy3 + 0.5f * (vt3 - Q3), gy0 + 0.5f * (vt0 - Q0));             // xbar
    } else if (sub == 5) {
        o4[5] = make_float4(gy1 + 0.5f * (vt1 - Q1), gy2 + 0.5f * (vt2 - Q2),
                            gy3 + 0.5f * (vt3 - Q3), gy0 + 0.5f * (vt0 - Q0));             // xbar
    } else if (sub == 6) {
        out[(size_t)B * 24 + b] = sqrtf(fmaxf(ip * im, 0.0f));                             // growth
    }
}

extern "C" void kernel_launch(void* const* d_in, const int* in_sizes, int n_in,
                              void* d_out, int out_size, void* d_ws, size_t ws_size,
                              hipStream_t stream) {
    const float* F4 = (const float*)d_in[0];
    const float* dx = (const float*)d_in[1];
    const float* dy = (const float*)d_in[2];
    const float* dz = (const float*)d_in[3];
    const float* qw = (const float*)d_in[4];
    float* out = (float*)d_out;

    int B = in_sizes[0] / 24;     // (B, 2, 3, 4)
    int ndir = in_sizes[1];       // 800
    float4* ws = (float4*)d_ws;   // B*4 float4 specs (2 MB at B=32768)

    int t1 = 4 * B;
    spec_kernel<<<(t1 + 255) / 256, 256, 0, stream>>>(F4, ws, B);
    int blocks = (B + 15) / 16;   // 16 batch elements per 256-thread block
    box3d_kernel<<<blocks, 256, 0, stream>>>(ws, dx, dy, dz, qw, out, B, ndir);
}

// Round 10
// 96.237 us; speedup vs baseline: 1.6197x; 1.0014x over previous
//
#include <hip/hip_runtime.h>
#include <math.h>

#define EPSF     1e-12f
#define INV_4PI  0.07957747154594767f
#define LOG2E    1.4426950408889634f

typedef float v2f __attribute__((ext_vector_type(2)));

#if __has_builtin(__builtin_elementwise_fma)
#define FMA2(a, b, c) __builtin_elementwise_fma((a), (b), (c))
#else
#define FMA2(a, b, c) ((a) * (b) + (c))
#endif

// raw hardware exp2: single v_exp_f32 (|arg| < ~50 here, no subnormal fixup needed)
#define EXP2(x) __builtin_amdgcn_exp2f(x)

// Z = z_approxbis(f), f already clipped to [0, 0.999999]
__device__ __forceinline__ float zapprox(float f) {
    float f2 = f * f;
    float f4 = f2 * f2;
    float f6 = f4 * f2;
    float f8 = f4 * f4;
    float denom = 3.0f - 1.00651f * f2 - 0.962251f * f4 + 1.47353f * f6 - 0.48953f * f8;
    denom = fmaxf(denom, EPSF);
    float p = 1.0f - 2.0f * (1.0f - f) * (1.0f + 1.01524f * f) / denom;
    return 2.0f * f / fmaxf(1.0f - p, 1e-6f);
}

// z / sinh(z), z >= 0
__device__ __forceinline__ float z_over_sinh(float z) {
    float zz = z * z;
    float series = 1.0f - zz / 6.0f + zz * zz / 120.0f;
    float E = __expf(z);
    float s = 0.5f * (E - 1.0f / E);
    float r = z / s;           // NaN at z==0, discarded by select
    return (z < 1e-4f) ? series : r;
}

// per-species: g(dir) = 2^(zx*dx + zy*dy + zz*dz + la)
__device__ __forceinline__ float4 setup_spec(float N, float Fx, float Fy, float Fz) {
    N = fmaxf(N, EPSF);
    float nf = sqrtf(Fx * Fx + Fy * Fy + Fz * Fz);
    float f  = fminf(fmaxf(nf / N, 0.0f), 0.999999f);
    float Z  = zapprox(f);
    float A  = N * INV_4PI * z_over_sinh(Z);
    float sc = Z * LOG2E / fmaxf(nf, EPSF);
    return make_float4(Fx * sc, Fy * sc, Fz * sc, log2f(A));
}

// ---- kernel 1: per-(batch,species) Spec precompute -> d_ws --------------
__global__ __launch_bounds__(256) void spec_kernel(
    const float* __restrict__ F4, float4* __restrict__ ws, int B)
{
    int t = blockIdx.x * blockDim.x + threadIdx.x;
    if (t >= 4 * B) return;
    int b = t >> 2, s = t & 3;
    const float4* row = (const float4*)(F4 + (size_t)b * 24);
    float N, Fx, Fy, Fz;
    if (s == 0) {                       // e
        float4 a = row[0];  N = a.w; Fx = a.x; Fy = a.y; Fz = a.z;
    } else if (s == 1) {                // ebar
        float4 a = row[3];  N = a.w; Fx = a.x; Fy = a.y; Fz = a.z;
    } else if (s == 2) {                // x = mean(flavors 1,2) of nu
        float4 a = row[1], c = row[2];
        N = 0.5f * (a.w + c.w); Fx = 0.5f * (a.x + c.x);
        Fy = 0.5f * (a.y + c.y); Fz = 0.5f * (a.z + c.z);
    } else {                            // xbar
        float4 a = row[4], c = row[5];
        N = 0.5f * (a.w + c.w); Fx = 0.5f * (a.x + c.x);
        Fy = 0.5f * (a.y + c.y); Fz = 0.5f * (a.z + c.z);
    }
    ws[(size_t)b * 4 + s] = setup_spec(N, Fx, Fy, Fz);
}

__device__ __forceinline__ v2f bcast(float x) { v2f r; r.x = x; r.y = x; return r; }

// ---- kernel 2: hot quadrature loop --------------------------------------
// launch_bounds min-waves/EU = 4: VGPR cap 128. Packed working set is ~106
// regs (48 accum + 32 const + ~26 temps) — fits in ARCH VGPRs, denying the
// allocator its AGPR-banking habit (R9: 52 VGPR + ~120 AGPR -> 2.9 waves/SIMD,
// latency-bound at ~30% issue). 4 waves/SIMD + pure-VGPR is the sweet spot.
__global__ __launch_bounds__(256, 4) void box3d_kernel(
    const float4* __restrict__ ws,
    const float* __restrict__ dxp, const float* __restrict__ dyp,
    const float* __restrict__ dzp, const float* __restrict__ qwp,
    float* __restrict__ out, int B, int ndir)
{
    // pair-interleaved LDS: per direction-pair p, two float4s
    //   sAB[p] = (qx0,qx1, qy0,qy1)   sCD[p] = (qz0,qz1, qw0,qw1)
    // -> 2 ds_read_b128 per iteration (was 4 ds_read_b64).
    // 16 lanes read consecutive p: 16B stride, 2-way bank aliasing (free);
    // the 4 groups in a wave read the same addresses (broadcast).
    __shared__ float4 sAB[400], sCD[400];
    const int npair = ndir >> 1;             // 400
    for (int p = threadIdx.x; p < npair; p += blockDim.x) {
        int d0 = 2 * p;
        sAB[p] = make_float4(dxp[d0], dxp[d0 + 1], dyp[d0], dyp[d0 + 1]);
        sCD[p] = make_float4(dzp[d0], dzp[d0 + 1], qwp[d0], qwp[d0 + 1]);
    }
    __syncthreads();

    const int sub = threadIdx.x & 15;        // lane within 16-group
    const int grp = threadIdx.x >> 4;        // 16 groups per 256-thread block
    const int b = blockIdx.x * 16 + grp;
    if (b >= B) return;

    // specs precomputed by spec_kernel
    const float4* wsb = ws + (size_t)b * 4;
    float4 f0 = wsb[0], f1 = wsb[1], f2 = wsb[2], f3 = wsb[3];
    v2f zx0 = bcast(f0.x), zy0 = bcast(f0.y), zz0 = bcast(f0.z), la0 = bcast(f0.w);
    v2f zx1 = bcast(f1.x), zy1 = bcast(f1.y), zz1 = bcast(f1.z), la1 = bcast(f1.w);
    v2f zx2 = bcast(f2.x), zy2 = bcast(f2.y), zz2 = bcast(f2.z), la2 = bcast(f2.w);
    v2f zx3 = bcast(f3.x), zy3 = bcast(f3.y), zz3 = bcast(f3.z), la3 = bcast(f3.w);

    // masked moment sums; ip/im derived afterwards from up0/vp0/ut0/vt0
    const v2f zero = bcast(0.0f);
    v2f aut0 = zero, aut1 = zero, aut2 = zero, aut3 = zero;
    v2f aup0 = zero, aup1 = zero, aup2 = zero, aup3 = zero;
    v2f avt0 = zero, avt1 = zero, avt2 = zero, avt3 = zero;
    v2f avp0 = zero, avp1 = zero, avp2 = zero, avp3 = zero;
    v2f agx0 = zero, agx1 = zero, agx2 = zero, agx3 = zero;
    v2f agy0 = zero, agy1 = zero, agy2 = zero, agy3 = zero;

    for (int p = sub; p < npair; p += 16) {
        float4 ab = sAB[p];
        float4 cd = sCD[p];
        v2f qx; qx.x = ab.x; qx.y = ab.y;
        v2f qy; qy.x = ab.z; qy.y = ab.w;
        v2f qz; qz.x = cd.x; qz.y = cd.y;
        v2f qw; qw.x = cd.z; qw.y = cd.w;

        v2f t0 = FMA2(zx0, qx, FMA2(zy0, qy, FMA2(zz0, qz, la0)));
        v2f t1 = FMA2(zx1, qx, FMA2(zy1, qy, FMA2(zz1, qz, la1)));
        v2f t2 = FMA2(zx2, qx, FMA2(zy2, qy, FMA2(zz2, qz, la2)));
        v2f t3 = FMA2(zx3, qx, FMA2(zy3, qy, FMA2(zz3, qz, la3)));
        v2f g0, g1, g2, g3;
        g0.x = EXP2(t0.x); g0.y = EXP2(t0.y);
        g1.x = EXP2(t1.x); g1.y = EXP2(t1.y);
        g2.x = EXP2(t2.x); g2.y = EXP2(t2.y);
        g3.x = EXP2(t3.x); g3.y = EXP2(t3.y);

        v2f u = g0 - g2, v = g1 - g3;        // delta = u - v; w > 0
        v2f wu = qw * u, wv = qw * v;
        v2f wup, wvp;                        // masked (delta >= 0) terms
        wup.x = (u.x >= v.x) ? wu.x : 0.0f;
        wup.y = (u.y >= v.y) ? wu.y : 0.0f;
        wvp.x = (u.x >= v.x) ? wv.x : 0.0f;
        wvp.y = (u.y >= v.y) ? wv.y : 0.0f;
        v2f w2 = qw * g2, w3 = qw * g3;

        aut0 += wu;  aup0 += wup;  avt0 += wv;  avp0 += wvp;  agx0 += w2;  agy0 += w3;
        aut1 = FMA2(wu, qx, aut1);  aup1 = FMA2(wup, qx, aup1);
        avt1 = FMA2(wv, qx, avt1);  avp1 = FMA2(wvp, qx, avp1);
        agx1 = FMA2(w2, qx, agx1);  agy1 = FMA2(w3, qx, agy1);
        aut2 = FMA2(wu, qy, aut2);  aup2 = FMA2(wup, qy, aup2);
        avt2 = FMA2(wv, qy, avt2);  avp2 = FMA2(wvp, qy, avp2);
        agx2 = FMA2(w2, qy, agx2);  agy2 = FMA2(w3, qy, agy2);
        aut3 = FMA2(wu, qz, aut3);  aup3 = FMA2(wup, qz, aup3);
        avt3 = FMA2(wv, qz, avt3);  avp3 = FMA2(wvp, qz, avp3);
        agx3 = FMA2(w2, qz, agx3);  agy3 = FMA2(w3, qz, agy3);
    }

    // ---- collapse packed pairs, then butterfly over the 16-lane group ----
    float ut0 = aut0.x + aut0.y, ut1 = aut1.x + aut1.y, ut2 = aut2.x + aut2.y, ut3 = aut3.x + aut3.y;
    float up0 = aup0.x + aup0.y, up1 = aup1.x + aup1.y, up2 = aup2.x + aup2.y, up3 = aup3.x + aup3.y;
    float vt0 = avt0.x + avt0.y, vt1 = avt1.x + avt1.y, vt2 = avt2.x + avt2.y, vt3 = avt3.x + avt3.y;
    float vp0 = avp0.x + avp0.y, vp1 = avp1.x + avp1.y, vp2 = avp2.x + avp2.y, vp3 = avp3.x + avp3.y;
    float gx0 = agx0.x + agx0.y, gx1 = agx1.x + agx1.y, gx2 = agx2.x + agx2.y, gx3 = agx3.x + agx3.y;
    float gy0 = agy0.x + agy0.y, gy1 = agy1.x + agy1.y, gy2 = agy2.x + agy2.y, gy3 = agy3.x + agy3.y;

    #pragma unroll
    for (int msk = 1; msk <= 8; msk <<= 1) {
        ut0 += __shfl_xor(ut0, msk);  ut1 += __shfl_xor(ut1, msk);
        ut2 += __shfl_xor(ut2, msk);  ut3 += __shfl_xor(ut3, msk);
        up0 += __shfl_xor(up0, msk);  up1 += __shfl_xor(up1, msk);
        up2 += __shfl_xor(up2, msk);  up3 += __shfl_xor(up3, msk);
        vt0 += __shfl_xor(vt0, msk);  vt1 += __shfl_xor(vt1, msk);
        vt2 += __shfl_xor(vt2, msk);  vt3 += __shfl_xor(vt3, msk);
        vp0 += __shfl_xor(vp0, msk);  vp1 += __shfl_xor(vp1, msk);
        vp2 += __shfl_xor(vp2, msk);  vp3 += __shfl_xor(vp3, msk);
        gx0 += __shfl_xor(gx0, msk);  gx1 += __shfl_xor(gx1, msk);
        gx2 += __shfl_xor(gx2, msk);  gx3 += __shfl_xor(gx3, msk);
        gy0 += __shfl_xor(gy0, msk);  gy1 += __shfl_xor(gy1, msk);
        gy2 += __shfl_xor(gy2, msk);  gy3 += __shfl_xor(gy3, msk);
    }

    // Iplus = sum_{delta>=0} w*delta = up0 - vp0 (identical masked sums)
    // Iminus = Iplus - sum w*delta   = ip - (ut0 - vt0)
    float ip = fmaxf(up0 - vp0, 0.0f);
    float im = fmaxf(ip - ut0 + vt0, 0.0f);

    float Ips = fmaxf(ip, EPSF), Ims = fmaxf(im, EPSF);
    const float third = 1.0f / 3.0f;
    float cp, cn;
    if (ip < im) {
        cp = third;
        cn = fminf(fmaxf(1.0f - (2.0f / 3.0f) * (Ips / Ims), 0.0f), 1.0f);
    } else {
        cp = fminf(fmaxf(1.0f - (2.0f / 3.0f) * (Ims / Ips), 0.0f), 1.0f);
        cn = third;
    }

    // ---- final moments: P = cp*up + cn*(ut-up); out per reference layout ----
    float P0 = cp * up0 + cn * (ut0 - up0), Q0 = cp * vp0 + cn * (vt0 - vp0);
    float P1 = cp * up1 + cn * (ut1 - up1), Q1 = cp * vp1 + cn * (vt1 - vp1);
    float P2 = cp * up2 + cn * (ut2 - up2), Q2 = cp * vp2 + cn * (vt2 - vp2);
    float P3 = cp * up3 + cn * (ut3 - up3), Q3 = cp * vp3 + cn * (vt3 - vp3);

    // memory layout per batch (6 float4): [e, x, x, ebar, xbar, xbar], each (Fx,Fy,Fz,N)
    float4* o4 = (float4*)out + (size_t)b * 6;
    if (sub == 0) {
        o4[0] = make_float4(gx1 + P1, gx2 + P2, gx3 + P3, gx0 + P0);                       // e
    } else if (sub == 1) {
        o4[1] = make_float4(gx1 + 0.5f * (ut1 - P1), gx2 + 0.5f * (ut2 - P2),
                            gx3 + 0.5f * (ut3 - P3), gx0 + 0.5f * (ut0 - P0));             // x
    } else if (sub == 2) {
        o4[2] = make_float4(gx1 + 0.5f * (ut1 - P1), gx2 + 0.5f * (ut2 - P2),
                            gx3 + 0.5f * (ut3 - P3), gx0 + 0.5f * (ut0 - P0));             // x
    } else if (sub == 3) {
        o4[3] = make_float4(gy1 + Q1, gy2 + Q2, gy3 + Q3, gy0 + Q0);                       // ebar
    } else if (sub == 4) {
        o4[4] = make_float4(gy1 + 0.5f * (vt1 - Q1), gy2 + 0.5f * (vt2 - Q2),
                            gy3 + 0.5f * (vt3 - Q3), gy0 + 0.5f * (vt0 - Q0));             // xbar
    } else if (sub == 5) {
        o4[5] = make_float4(gy1 + 0.5f * (vt1 - Q1), gy2 + 0.5f * (vt2 - Q2),
                            gy3 + 0.5f * (vt3 - Q3), gy0 + 0.5f * (vt0 - Q0));             // xbar
    } else if (sub == 6) {
        out[(size_t)B * 24 + b] = sqrtf(fmaxf(ip * im, 0.0f));                             // growth
    }
}

extern "C" void kernel_launch(void* const* d_in, const int* in_sizes, int n_in,
                              void* d_out, int out_size, void* d_ws, size_t ws_size,
                              hipStream_t stream) {
    const float* F4 = (const float*)d_in[0];
    const float* dx = (const float*)d_in[1];
    const float* dy = (const float*)d_in[2];
    const float* dz = (const float*)d_in[3];
    const float* qw = (const float*)d_in[4];
    float* out = (float*)d_out;

    int B = in_sizes[0] / 24;     // (B, 2, 3, 4)
    int ndir = in_sizes[1];       // 800
    float4* ws = (float4*)d_ws;   // B*4 float4 specs (2 MB at B=32768)

    int t1 = 4 * B;
    spec_kernel<<<(t1 + 255) / 256, 256, 0, stream>>>(F4, ws, B);
    int blocks = (B + 15) / 16;   // 16 batch elements per 256-thread block
    box3d_kernel<<<blocks, 256, 0, stream>>>(ws, dx, dy, dz, qw, out, B, ndir);
}